// Round 5
// baseline (299.661 us; speedup 1.0000x reference)
//
#include <hip/hip_runtime.h>
#include <math.h>

#define G      1708
#define NH     5
#define NB     16
#define NC     34
#define NCH    427
#define JSL    8            // j-slices (threads) per i-group
#define ITR    2            // i-values per thread
#define IPB    64           // i per block
#define IBLK   27           // ceil(G/IPB)
#define JCHMAX 244
#define LN_EPS 1e-6f
#define LOG2E  1.4426950408889634f

// monotone float<->uint key map for atomic min/max on floats
__device__ __forceinline__ unsigned enc(float f) {
    unsigned u = __float_as_uint(f);
    return (u & 0x80000000u) ? ~u : (u | 0x80000000u);
}
__device__ __forceinline__ float dec(unsigned k) {
    return (k & 0x80000000u) ? __uint_as_float(k ^ 0x80000000u)
                             : __uint_as_float(~k);
}

// ---------------------------------------------------------------------------
// Layer-1 k-table min/max: one block per (h,b). Writes encoded keys.
// Also zeroes stats slot 0 (h==0 block of each b).
// ---------------------------------------------------------------------------
__global__ __launch_bounds__(256) void minmax_kernel(
    const float* __restrict__ hin, const float* __restrict__ WK,
    unsigned* __restrict__ kmm, float* __restrict__ stats)
{
    const int h = blockIdx.x, b = blockIdx.y, tid = threadIdx.x;
    float mx = -INFINITY, mn = INFINITY;
    for (int j = tid; j < G; j += 256) {
        float kl = hin[(size_t)b * G + j] * WK[(size_t)h * G + j] * LOG2E;
        mx = fmaxf(mx, kl);
        mn = fminf(mn, kl);
    }
    for (int o = 1; o < 64; o <<= 1) {
        mx = fmaxf(mx, __shfl_xor(mx, o));
        mn = fminf(mn, __shfl_xor(mn, o));
    }
    __shared__ float smx[4], smn[4];
    if ((tid & 63) == 0) { smx[tid >> 6] = mx; smn[tid >> 6] = mn; }
    __syncthreads();
    if (tid == 0) {
        mx = fmaxf(fmaxf(smx[0], smx[1]), fmaxf(smx[2], smx[3]));
        mn = fminf(fminf(smn[0], smn[1]), fminf(smn[2], smn[3]));
        kmm[(b * NH + h) * 2 + 0] = enc(mx);
        kmm[(b * NH + h) * 2 + 1] = enc(mn);
        if (h == 0) { stats[b * 2] = 0.f; stats[b * 2 + 1] = 0.f; }
    }
}

// ---------------------------------------------------------------------------
// Partial softmax sums for one j-chunk (rank-1 row max => partials addable).
// grid (IBLK, jbn, NB), 256 threads.
// ---------------------------------------------------------------------------
__global__ __launch_bounds__(256) void attn_partial(
    const float* __restrict__ hin, const float* __restrict__ WQ,
    const float* __restrict__ WK, const float* __restrict__ WV,
    const unsigned* __restrict__ kmm,
    float* __restrict__ S1p, float* __restrict__ S2p, int jch)
{
    __shared__ float kc[NH][JCHMAX];
    __shared__ float vc[NH][JCHMAX];

    const int b = blockIdx.z, jb = blockIdx.y, jbn = gridDim.y;
    const int tid = threadIdx.x;
    const int jg = jb * jch;
    const int cnt = min(jch, G - jg);          // divisible by 4

    for (int h = 0; h < NH; ++h)
        for (int j = tid; j < cnt; j += 256) {
            float xv = hin[(size_t)b * G + jg + j];
            kc[h][j] = xv * WK[(size_t)h * G + jg + j] * LOG2E;
            vc[h][j] = xv * WV[(size_t)h * G + jg + j];
        }
    __syncthreads();

    const int ig = tid >> 3, sl = tid & 7;
    const int i0 = blockIdx.x * IPB + ig * ITR;
    const bool valid = i0 < G;                 // i0 even, G even
    const int is = valid ? i0 : 0;

    const float2 xi2 = *reinterpret_cast<const float2*>(hin + (size_t)b * G + is);

    float q[ITR][NH], m[ITR][NH], S1[ITR][NH], S2[ITR][NH];
#pragma unroll
    for (int h = 0; h < NH; ++h) {
        float kx = dec(kmm[(b * NH + h) * 2 + 0]);
        float kn = dec(kmm[(b * NH + h) * 2 + 1]);
        float2 wq = *reinterpret_cast<const float2*>(WQ + (size_t)h * G + is);
        q[0][h] = xi2.x * wq.x;
        q[1][h] = xi2.y * wq.y;
#pragma unroll
        for (int r = 0; r < ITR; ++r) {
            m[r][h]  = fmaxf(q[r][h] * kx, q[r][h] * kn);
            S1[r][h] = 0.f;
            S2[r][h] = 0.f;
        }
    }

    const int cnt4 = cnt >> 2;
    for (int c = sl; c < cnt4; c += JSL) {
#pragma unroll
        for (int h = 0; h < NH; ++h) {
            float4 kk = reinterpret_cast<const float4*>(kc[h])[c];
            float4 vq = reinterpret_cast<const float4*>(vc[h])[c];
#pragma unroll
            for (int r = 0; r < ITR; ++r) {
                float qq = q[r][h], mm = m[r][h];
                float e0 = __builtin_amdgcn_exp2f(fmaf(qq, kk.x, -mm));
                float e1 = __builtin_amdgcn_exp2f(fmaf(qq, kk.y, -mm));
                float e2 = __builtin_amdgcn_exp2f(fmaf(qq, kk.z, -mm));
                float e3 = __builtin_amdgcn_exp2f(fmaf(qq, kk.w, -mm));
                S1[r][h] += (e0 + e1) + (e2 + e3);
                S2[r][h] += (e0 * vq.x + e1 * vq.y) + (e2 * vq.z + e3 * vq.w);
            }
        }
    }

#pragma unroll
    for (int r = 0; r < ITR; ++r)
#pragma unroll
        for (int h = 0; h < NH; ++h)
            for (int o = 1; o < JSL; o <<= 1) {
                S1[r][h] += __shfl_xor(S1[r][h], o);
                S2[r][h] += __shfl_xor(S2[r][h], o);
            }

    if (sl == 0 && valid) {
#pragma unroll
        for (int h = 0; h < NH; ++h) {
            size_t base = ((size_t)(b * jbn + jb) * NH + h) * G + i0;
            *reinterpret_cast<float2*>(S1p + base) = make_float2(S1[0][h], S1[1][h]);
            *reinterpret_cast<float2*>(S2p + base) = make_float2(S2[0][h], S2[1][h]);
        }
    }
}

// ---------------------------------------------------------------------------
// Combine partials + diagonal correction; atomically accumulate LN stats
// (sum, sumsq) for this layer; initialize next layer's kmm keys.
// grid (7, NB), 256 threads.
// ---------------------------------------------------------------------------
__global__ __launch_bounds__(256) void attn_combine(
    const float* __restrict__ hin, const float* __restrict__ WQ,
    const float* __restrict__ WK, const float* __restrict__ WV,
    const float* __restrict__ W0, const unsigned* __restrict__ kmm,
    const float* __restrict__ S1p, const float* __restrict__ S2p,
    float* __restrict__ aout, float* __restrict__ stats,
    unsigned* __restrict__ kmm_next, int jbn)
{
    const int b = blockIdx.y;
    const int tid = threadIdx.x;
    const int i = blockIdx.x * 256 + tid;

    float av = 0.f;
    if (i < G) {
        const float xi = hin[(size_t)b * G + i];
        float acc = 0.f;
#pragma unroll
        for (int h = 0; h < NH; ++h) {
            float S1 = 0.f, S2 = 0.f;
            for (int jb = 0; jb < jbn; ++jb) {
                size_t base = ((size_t)(b * jbn + jb) * NH + h) * G + i;
                S1 += S1p[base];
                S2 += S2p[base];
            }
            float q   = xi * WQ[(size_t)h * G + i];
            float kli = xi * WK[(size_t)h * G + i] * LOG2E;
            float vvi = xi * WV[(size_t)h * G + i];
            float kx  = dec(kmm[(b * NH + h) * 2 + 0]);
            float kn  = dec(kmm[(b * NH + h) * 2 + 1]);
            float mm  = fmaxf(q * kx, q * kn);
            float eii = __builtin_amdgcn_exp2f(fmaf(q, kli, -mm));
            acc += W0[h] * (S2 - eii * vvi) / S1;
        }
        aout[(size_t)b * G + i] = acc;
        av = acc;
    }

    // block-reduce sum & sumsq, one atomicAdd pair per block
    float s = av, ss = av * av;
    for (int o = 1; o < 64; o <<= 1) {
        s  += __shfl_xor(s, o);
        ss += __shfl_xor(ss, o);
    }
    __shared__ float rs[4], rss[4];
    if ((tid & 63) == 0) { rs[tid >> 6] = s; rss[tid >> 6] = ss; }
    __syncthreads();
    if (tid == 0) {
        atomicAdd(&stats[b * 2 + 0], (rs[0] + rs[1]) + (rs[2] + rs[3]));
        atomicAdd(&stats[b * 2 + 1], (rss[0] + rss[1]) + (rss[2] + rss[3]));
    }
    // init next layer's kmm keys (identical-value benign race across blocks)
    if (tid < NH) {
        kmm_next[(b * NH + tid) * 2 + 0] = 0u;           // max slot: -inf key
        kmm_next[(b * NH + tid) * 2 + 1] = 0xFFFFFFFFu;  // min slot: +inf key
    }
}

// ---------------------------------------------------------------------------
// Elementwise LN-apply: h = base + ga*(a-mean)*inv + gb; atomically min/max
// next layer's k-table; zero next layer's stats. grid (7, NB).
// ---------------------------------------------------------------------------
__global__ __launch_bounds__(256) void ln_apply(
    const float* __restrict__ base, const float* __restrict__ a,
    const float* __restrict__ ga, const float* __restrict__ gb,
    float* __restrict__ hout, const float* __restrict__ stats,
    const float* __restrict__ WKn, unsigned* __restrict__ kmm_next,
    float* __restrict__ stats_next)
{
    const int b = blockIdx.y;
    const int tid = threadIdx.x;
    const int i = blockIdx.x * 256 + tid;

    const float S  = stats[b * 2 + 0];
    const float SS = stats[b * 2 + 1];
    const float mean = S / (float)G;
    const float var  = fmaxf((SS - S * mean) / (float)(G - 1), 0.f);
    const float inv  = 1.f / (sqrtf(var) + LN_EPS);

    float hv = 0.f;
    const bool vld = i < G;
    if (vld) {
        float v = a[(size_t)b * G + i];
        hv = base[(size_t)b * G + i] + ga[i] * (v - mean) * inv + gb[i];
        hout[(size_t)b * G + i] = hv;
    }

    float mx[NH], mn[NH];
#pragma unroll
    for (int h = 0; h < NH; ++h) {
        float kl = vld ? hv * WKn[(size_t)h * G + i] * LOG2E : 0.f;
        mx[h] = vld ? kl : -INFINITY;
        mn[h] = vld ? kl : INFINITY;
    }
#pragma unroll
    for (int h = 0; h < NH; ++h)
        for (int o = 1; o < 64; o <<= 1) {
            mx[h] = fmaxf(mx[h], __shfl_xor(mx[h], o));
            mn[h] = fminf(mn[h], __shfl_xor(mn[h], o));
        }
    __shared__ float rmx[NH][4], rmn[NH][4];
    if ((tid & 63) == 0) {
#pragma unroll
        for (int h = 0; h < NH; ++h) {
            rmx[h][tid >> 6] = mx[h];
            rmn[h][tid >> 6] = mn[h];
        }
    }
    __syncthreads();
    if (tid < NH) {
        float bx = fmaxf(fmaxf(rmx[tid][0], rmx[tid][1]), fmaxf(rmx[tid][2], rmx[tid][3]));
        float bn = fminf(fminf(rmn[tid][0], rmn[tid][1]), fminf(rmn[tid][2], rmn[tid][3]));
        atomicMax(&kmm_next[(b * NH + tid) * 2 + 0], enc(bx));
        atomicMin(&kmm_next[(b * NH + tid) * 2 + 1], enc(bn));
    }
    if (tid == 0) {  // identical-value benign race
        stats_next[b * 2 + 0] = 0.f;
        stats_next[b * 2 + 1] = 0.f;
    }
}

// ---------------------------------------------------------------------------
__global__ __launch_bounds__(64) void logits_kernel(
    const float* __restrict__ h, const float* __restrict__ fw,
    const float* __restrict__ fb, float* __restrict__ logits)
{
    const int c = blockIdx.x, b = blockIdx.y;
    const int lane = threadIdx.x;
    const float4* h4 = reinterpret_cast<const float4*>(h + (size_t)b * G);
    const float4* w4 = reinterpret_cast<const float4*>(fw + (size_t)c * G);
    float s = 0.f;
    for (int k = lane; k < NCH; k += 64) {
        float4 av = h4[k], w = w4[k];
        s += (av.x * w.x + av.y * w.y) + (av.z * w.z + av.w * w.w);
    }
    for (int o = 32; o; o >>= 1) s += __shfl_down(s, o);
    if (lane == 0) logits[(size_t)b * NC + c] = s + fb[c];
}

__global__ __launch_bounds__(64) void lsm_kernel(
    const float* __restrict__ logits, float* __restrict__ out)
{
    const int b = blockIdx.x, tid = threadIdx.x;
    float l = (tid < NC) ? logits[(size_t)b * NC + tid] : -INFINITY;
    float mm = l;
    for (int o = 32; o; o >>= 1) mm = fmaxf(mm, __shfl_xor(mm, o));
    float e = (tid < NC) ? expf(l - mm) : 0.f;
    float se = e;
    for (int o = 32; o; o >>= 1) se += __shfl_xor(se, o);
    if (tid < NC) out[(size_t)b * NC + tid] = l - mm - logf(se);
}

// ---------------------------------------------------------------------------
extern "C" void kernel_launch(void* const* d_in, const int* in_sizes, int n_in,
                              void* d_out, int out_size, void* d_ws, size_t ws_size,
                              hipStream_t stream)
{
    const float* x    = (const float*)d_in[0];
    const float* WQ1  = (const float*)d_in[1];
    const float* WK1  = (const float*)d_in[2];
    const float* WV1  = (const float*)d_in[3];
    const float* W01  = (const float*)d_in[4];
    const float* WQ2  = (const float*)d_in[5];
    const float* WK2  = (const float*)d_in[6];
    const float* WV2  = (const float*)d_in[7];
    const float* W02  = (const float*)d_in[8];
    const float* WQ3  = (const float*)d_in[9];
    const float* WK3  = (const float*)d_in[10];
    const float* WV3  = (const float*)d_in[11];
    const float* W03  = (const float*)d_in[12];
    const float* ln_a = (const float*)d_in[13];
    const float* ln_b = (const float*)d_in[14];
    const float* fc_w = (const float*)d_in[15];
    const float* fc_b = (const float*)d_in[16];
    float* out = (float*)d_out;

    float*    a      = (float*)d_ws;                    // [NB,G]
    float*    h      = a + (size_t)NB * G;              // [NB,G]
    float*    logits = h + (size_t)NB * G;              // [NB,NC]
    unsigned* kmm    = (unsigned*)(logits + NB * NC);   // 4 slots x [NB,NH,2]
    float*    stats  = (float*)(kmm + 4 * NB * NH * 2); // 4 slots x [NB,2]
    float*    S1p    = stats + 4 * NB * 2;

    // pick j-split granularity by workspace budget
    const size_t fixed = ((size_t)2 * NB * G + NB * NC + 4 * NB * NH * 2 + 4 * NB * 2) * 4;
    const size_t need11 = fixed + (size_t)2 * NB * 11 * NH * G * 4;
    const int jbn = (ws_size >= need11) ? 11 : 7;
    const int jch = (jbn == 11) ? 160 : 244;
    float* S2p = S1p + (size_t)NB * jbn * NH * G;

    const int KS = NB * NH * 2;                         // kmm slot stride
    const int SS = NB * 2;                              // stats slot stride
    const dim3 pgrid(IBLK, jbn, NB);
    const dim3 egrid((G + 255) / 256, NB);              // (7,16)

    minmax_kernel<<<dim3(NH, NB), 256, 0, stream>>>(x, WK1, kmm, stats);

    attn_partial<<<pgrid, 256, 0, stream>>>(x, WQ1, WK1, WV1, kmm, S1p, S2p, jch);
    attn_combine<<<egrid, 256, 0, stream>>>(x, WQ1, WK1, WV1, W01, kmm, S1p, S2p,
                                            a, stats, kmm + KS, jbn);
    ln_apply<<<egrid, 256, 0, stream>>>(x, a, ln_a, ln_b, h, stats, WK2,
                                        kmm + KS, stats + SS);

    attn_partial<<<pgrid, 256, 0, stream>>>(h, WQ2, WK2, WV2, kmm + KS, S1p, S2p, jch);
    attn_combine<<<egrid, 256, 0, stream>>>(h, WQ2, WK2, WV2, W02, kmm + KS, S1p, S2p,
                                            a, stats + SS, kmm + 2 * KS, jbn);
    ln_apply<<<egrid, 256, 0, stream>>>(h, a, ln_a, ln_b, h, stats + SS, WK3,
                                        kmm + 2 * KS, stats + 2 * SS);

    attn_partial<<<pgrid, 256, 0, stream>>>(h, WQ3, WK3, WV3, kmm + 2 * KS, S1p, S2p, jch);
    attn_combine<<<egrid, 256, 0, stream>>>(h, WQ3, WK3, WV3, W03, kmm + 2 * KS, S1p, S2p,
                                            a, stats + 2 * SS, kmm + 3 * KS, jbn);
    ln_apply<<<egrid, 256, 0, stream>>>(h, a, ln_a, ln_b, h, stats + 2 * SS, WK1,
                                        kmm + 3 * KS, stats + 3 * SS);

    logits_kernel<<<dim3(NC, NB), 64, 0, stream>>>(h, fc_w, fc_b, logits);
    lsm_kernel<<<NB, 64, 0, stream>>>(logits, out);
}